// Round 14
// baseline (213.414 us; speedup 1.0000x reference)
//
#include <hip/hip_runtime.h>
#include <hip/hip_bf16.h>

// Problem constants (from the reference)
#define N_IN_SZ   (721 * 1440)   // 1,038,240
#define N_ROWS    (361 * 720)    //   259,920 output cells
#define BC        64             // B*C = 4*16
#define ROW_CAP   16             // padded entries per row (lambda=4.03)
#define OF_CAP    4096
#define TCOLS     256            // transpose tile: 64 bc x 256 cols

__device__ __forceinline__ unsigned short bf16_bits(float a) {
    __hip_bfloat16 h = __float2bfloat16(a);
    return *(unsigned short*)&h;
}

// ---------------- fused prep: scatter (every 5th block) || transpose ----------------
// transpose: tile = 64 bc x 256 cols. Load: wave owns 16 bc-rows; each row is ONE
// float4 wave-instr = 1 KB CONTIGUOUS from x (DRAM-page friendly; 16 independent
// loads in flight/wave). Convert to bf16 at load, stage in LDS [64][258] ushort
// (33 KB -> 4 blocks/CU). Store: 512B contiguous per wave-instr, 32 KB/block.

__global__ void prep_kernel(const float* __restrict__ x,
                            const int* __restrict__ rows, const int* __restrict__ cols,
                            const float* __restrict__ S,
                            int* __restrict__ cursor, int2* __restrict__ epad,
                            int* __restrict__ of_count, int4* __restrict__ of_list,
                            __hip_bfloat16* __restrict__ xt,
                            int nnz) {
    __shared__ unsigned short tile[64][258];   // bf16 bits, [bc][colOff], pad=2
    const int bid = blockIdx.x;

    if ((bid % 5) == 4) {
        // ---- scatter part (interleaved through the dispatch) ----
        const int nsc = gridDim.x / 5;
        const int stride = nsc * 256;
        for (int k = (bid / 5) * 256 + threadIdx.x; k < nnz; k += stride) {
            const int r = rows[k];
            const int slot = atomicAdd(&cursor[r], 1);
            if (slot < ROW_CAP) {
                epad[(size_t)r * ROW_CAP + slot] = make_int2(cols[k], __float_as_int(S[k]));
            } else {
                int o = atomicAdd(of_count, 1);
                if (o < OF_CAP) of_list[o] = make_int4(r, cols[k], __float_as_int(S[k]), 0);
            }
        }
        return;
    }

    // ---- transpose part ----
    const int t_idx = bid - (bid + 1) / 5;     // 0 .. nTiles-1
    const int c0 = t_idx * TCOLS;
    if (c0 >= N_IN_SZ) return;
    const int lane = threadIdx.x & 63;
    const int wave = threadIdx.x >> 6;         // 0..3

    if (c0 + TCOLS <= N_IN_SZ) {
        // fast path: one 1KB-contiguous float4 wave-load per bc-row, 16 rows/wave
        #pragma unroll
        for (int i = 0; i < 16; ++i) {
            const int bc = wave * 16 + i;
            const float4 v = *(const float4*)&x[(size_t)bc * N_IN_SZ + c0 + 4 * lane];
            ushort2 p0, p1;
            p0.x = bf16_bits(v.x); p0.y = bf16_bits(v.y);
            p1.x = bf16_bits(v.z); p1.y = bf16_bits(v.w);
            *(ushort2*)&tile[bc][4 * lane]     = p0;
            *(ushort2*)&tile[bc][4 * lane + 2] = p1;
        }
    } else {
        // tail tile (one block): scalar guarded
        #pragma unroll
        for (int i = 0; i < 16; ++i) {
            const int bc = wave * 16 + i;
            #pragma unroll
            for (int j = 0; j < 4; ++j) {
                const int c = c0 + 4 * lane + j;
                tile[bc][4 * lane + j] = (c < N_IN_SZ) ? bf16_bits(x[(size_t)bc * N_IN_SZ + c]) : 0;
            }
        }
    }
    __syncthreads();

    // store: lane -> (col = wave*64 + i*4 + (lane>>4), bc4 = 4*(lane&15));
    // each wave-instr writes 4 cols x 64 bc = 512B contiguous; block = 32 KB contiguous.
    #pragma unroll
    for (int i = 0; i < 16; ++i) {
        const int cl = wave * 64 + i * 4 + (lane >> 4);
        const int c = c0 + cl;
        if (c < N_IN_SZ) {
            const int bc4 = 4 * (lane & 15);
            ushort4 o;
            o.x = tile[bc4 + 0][cl];
            o.y = tile[bc4 + 1][cl];
            o.z = tile[bc4 + 2][cl];
            o.w = tile[bc4 + 3][cl];
            *(ushort4*)&xt[(size_t)c * 64 + bc4] = o;
        }
    }
}

// ---------------- gather (R12, proven): 4 streams x batch-4 = 16 loads in flight ----

__global__ void gather_kernel(const __hip_bfloat16* __restrict__ xt,
                              const int* __restrict__ cursor,
                              const int2* __restrict__ epad,
                              float* __restrict__ y) {
    __shared__ float tile[64][65];
    __shared__ int cnt[64];
    const int b = blockIdx.x;
    const int base = b * 64;
    const int lane = threadIdx.x & 63;
    const int wave = threadIdx.x >> 6;

    if (threadIdx.x < 64) {
        const int r = base + threadIdx.x;
        int cc = (r < N_ROWS) ? cursor[r] : 0;
        cnt[threadIdx.x] = (cc > ROW_CAP) ? ROW_CAP : cc;
    }
    __syncthreads();

    for (int rr = 0; rr < 4; ++rr) {
        const int r0 = wave * 16 + rr;
        const int r1 = r0 + 4;
        const int r2 = r0 + 8;
        const int r3 = r0 + 12;
        const int c0 = cnt[r0], c1 = cnt[r1], c2 = cnt[r2], c3 = cnt[r3];
        const int2* __restrict__ e0 = epad + (size_t)(base + r0) * ROW_CAP;
        const int2* __restrict__ e1 = epad + (size_t)(base + r1) * ROW_CAP;
        const int2* __restrict__ e2 = epad + (size_t)(base + r2) * ROW_CAP;
        const int2* __restrict__ e3 = epad + (size_t)(base + r3) * ROW_CAP;
        float a0 = 0.f, a1 = 0.f, a2 = 0.f, a3 = 0.f;
        int t0 = 0, t1 = 0, t2 = 0, t3 = 0;
        while (t0 < c0 || t1 < c1 || t2 < c2 || t3 < c3) {
            const bool g0 = (t0 < c0), g1 = (t1 < c1), g2 = (t2 < c2), g3 = (t3 < c3);
            const int4 z4 = make_int4(0, 0, 0, 0);
            int4 p00 = g0 ? *(const int4*)(e0 + t0)     : z4;
            int4 p01 = g0 ? *(const int4*)(e0 + t0 + 2) : z4;
            int4 p10 = g1 ? *(const int4*)(e1 + t1)     : z4;
            int4 p11 = g1 ? *(const int4*)(e1 + t1 + 2) : z4;
            int4 p20 = g2 ? *(const int4*)(e2 + t2)     : z4;
            int4 p21 = g2 ? *(const int4*)(e2 + t2 + 2) : z4;
            int4 p30 = g3 ? *(const int4*)(e3 + t3)     : z4;
            int4 p31 = g3 ? *(const int4*)(e3 + t3 + 2) : z4;
            float x00 = __bfloat162float(xt[(size_t)((t0 + 0 < c0) ? p00.x : 0) * 64 + lane]);
            float x01 = __bfloat162float(xt[(size_t)((t0 + 1 < c0) ? p00.z : 0) * 64 + lane]);
            float x02 = __bfloat162float(xt[(size_t)((t0 + 2 < c0) ? p01.x : 0) * 64 + lane]);
            float x03 = __bfloat162float(xt[(size_t)((t0 + 3 < c0) ? p01.z : 0) * 64 + lane]);
            float x10 = __bfloat162float(xt[(size_t)((t1 + 0 < c1) ? p10.x : 0) * 64 + lane]);
            float x11 = __bfloat162float(xt[(size_t)((t1 + 1 < c1) ? p10.z : 0) * 64 + lane]);
            float x12 = __bfloat162float(xt[(size_t)((t1 + 2 < c1) ? p11.x : 0) * 64 + lane]);
            float x13 = __bfloat162float(xt[(size_t)((t1 + 3 < c1) ? p11.z : 0) * 64 + lane]);
            float x20 = __bfloat162float(xt[(size_t)((t2 + 0 < c2) ? p20.x : 0) * 64 + lane]);
            float x21 = __bfloat162float(xt[(size_t)((t2 + 1 < c2) ? p20.z : 0) * 64 + lane]);
            float x22 = __bfloat162float(xt[(size_t)((t2 + 2 < c2) ? p21.x : 0) * 64 + lane]);
            float x23 = __bfloat162float(xt[(size_t)((t2 + 3 < c2) ? p21.z : 0) * 64 + lane]);
            float x30 = __bfloat162float(xt[(size_t)((t3 + 0 < c3) ? p30.x : 0) * 64 + lane]);
            float x31 = __bfloat162float(xt[(size_t)((t3 + 1 < c3) ? p30.z : 0) * 64 + lane]);
            float x32 = __bfloat162float(xt[(size_t)((t3 + 2 < c3) ? p31.x : 0) * 64 + lane]);
            float x33 = __bfloat162float(xt[(size_t)((t3 + 3 < c3) ? p31.z : 0) * 64 + lane]);
            a0 += ((t0 + 0 < c0) ? __int_as_float(p00.y) : 0.f) * x00;
            a0 += ((t0 + 1 < c0) ? __int_as_float(p00.w) : 0.f) * x01;
            a0 += ((t0 + 2 < c0) ? __int_as_float(p01.y) : 0.f) * x02;
            a0 += ((t0 + 3 < c0) ? __int_as_float(p01.w) : 0.f) * x03;
            a1 += ((t1 + 0 < c1) ? __int_as_float(p10.y) : 0.f) * x10;
            a1 += ((t1 + 1 < c1) ? __int_as_float(p10.w) : 0.f) * x11;
            a1 += ((t1 + 2 < c1) ? __int_as_float(p11.y) : 0.f) * x12;
            a1 += ((t1 + 3 < c1) ? __int_as_float(p11.w) : 0.f) * x13;
            a2 += ((t2 + 0 < c2) ? __int_as_float(p20.y) : 0.f) * x20;
            a2 += ((t2 + 1 < c2) ? __int_as_float(p20.w) : 0.f) * x21;
            a2 += ((t2 + 2 < c2) ? __int_as_float(p21.y) : 0.f) * x22;
            a2 += ((t2 + 3 < c2) ? __int_as_float(p21.w) : 0.f) * x23;
            a3 += ((t3 + 0 < c3) ? __int_as_float(p30.y) : 0.f) * x30;
            a3 += ((t3 + 1 < c3) ? __int_as_float(p30.w) : 0.f) * x31;
            a3 += ((t3 + 2 < c3) ? __int_as_float(p31.y) : 0.f) * x32;
            a3 += ((t3 + 3 < c3) ? __int_as_float(p31.w) : 0.f) * x33;
            if (g0) t0 += 4;
            if (g1) t1 += 4;
            if (g2) t2 += 4;
            if (g3) t3 += 4;
        }
        tile[lane][r0] = a0;
        tile[lane][r1] = a1;
        tile[lane][r2] = a2;
        tile[lane][r3] = a3;
    }
    __syncthreads();

    #pragma unroll
    for (int j = 0; j < 4; ++j) {
        const int task = j * 256 + threadIdx.x;
        const int bc = task >> 4;
        const int r0 = (task & 15) * 4;
        const int i0 = base + r0;
        float4 v = make_float4(tile[bc][r0], tile[bc][r0 + 1],
                               tile[bc][r0 + 2], tile[bc][r0 + 3]);
        float* yp = y + (size_t)bc * N_ROWS;
        if (i0 + 3 < N_ROWS) {
            *(float4*)&yp[i0] = v;
        } else {
            if (i0 + 0 < N_ROWS) yp[i0 + 0] = v.x;
            if (i0 + 1 < N_ROWS) yp[i0 + 1] = v.y;
            if (i0 + 2 < N_ROWS) yp[i0 + 2] = v.z;
            if (i0 + 3 < N_ROWS) yp[i0 + 3] = v.w;
        }
    }
}

// ---------------- overflow cleanup (expected ~0 entries) ----------------

__global__ void cleanup_kernel(const int* __restrict__ of_count,
                               const int4* __restrict__ of_list,
                               const float* __restrict__ x, float* __restrict__ y) {
    int n = *of_count;
    if (n > OF_CAP) n = OF_CAP;
    const int total = n * 64;
    for (int t = blockIdx.x * blockDim.x + threadIdx.x; t < total;
         t += gridDim.x * blockDim.x) {
        const int e = t >> 6, bc = t & 63;
        const int4 E = of_list[e];
        atomicAdd(&y[(size_t)bc * N_ROWS + E.x],
                  __int_as_float(E.z) * x[(size_t)bc * N_IN_SZ + E.y]);
    }
}

// ---------------- last-resort atomic COO ----------------

__global__ void regrid_coo_kernel(const float* __restrict__ x, const float* __restrict__ S,
                                  const int* __restrict__ rows, const int* __restrict__ cols,
                                  float* __restrict__ y, int nnz) {
    const int bc = blockIdx.y;
    const float* __restrict__ xp = x + (size_t)bc * N_IN_SZ;
    float* __restrict__ yp = y + (size_t)bc * N_ROWS;
    int k = blockIdx.x * blockDim.x + threadIdx.x;
    const int stride = gridDim.x * blockDim.x;
    for (; k < nnz; k += stride) {
        atomicAdd(&yp[rows[k]], S[k] * xp[cols[k]]);
    }
}

extern "C" void kernel_launch(void* const* d_in, const int* in_sizes, int n_in,
                              void* d_out, int out_size, void* d_ws, size_t ws_size,
                              hipStream_t stream) {
    const float* x    = (const float*)d_in[0];
    const float* S    = (const float*)d_in[1];
    const int*   rows = (const int*)d_in[2];
    const int*   cols = (const int*)d_in[3];
    float*       y    = (float*)d_out;
    const int nnz = in_sizes[1];

    // Workspace layout (256B-aligned chunks)
    const size_t SZ_CURSOR = ((size_t)N_ROWS * 4 + 255) & ~255ULL;             // 1.04 MB
    const size_t SZ_OFCNT  = 256;
    const size_t SZ_OFLIST = ((size_t)OF_CAP * 16 + 255) & ~255ULL;            // 64 KB
    const size_t SZ_EPAD   = ((size_t)N_ROWS * ROW_CAP * 8 + 255) & ~255ULL;   // 33.3 MB
    const size_t SZ_XT     = ((size_t)N_IN_SZ * BC * 2 + 255) & ~255ULL;       // 133 MB
    const size_t NEED = SZ_CURSOR + SZ_OFCNT + SZ_OFLIST + SZ_EPAD + SZ_XT;

    if (ws_size < NEED) {
        hipMemsetAsync(d_out, 0, (size_t)out_size * sizeof(float), stream);
        dim3 grid(1024, BC, 1);
        regrid_coo_kernel<<<grid, 256, 0, stream>>>(x, S, rows, cols, y, nnz);
        return;
    }

    char* w = (char*)d_ws;
    int*  cursor   = (int*)(w);
    int*  of_count = (int*)(w + SZ_CURSOR);
    int4* of_list  = (int4*)(w + SZ_CURSOR + SZ_OFCNT);
    int2* epad     = (int2*)(w + SZ_CURSOR + SZ_OFCNT + SZ_OFLIST);
    __hip_bfloat16* xt = (__hip_bfloat16*)(w + SZ_CURSOR + SZ_OFCNT + SZ_OFLIST + SZ_EPAD);

    // zero cursors + overflow count in one memset (contiguous)
    hipMemsetAsync(cursor, 0, SZ_CURSOR + SZ_OFCNT, stream);

    // fused prep: 256-col tiles + ~1/4 as many scatter blocks, interleaved 1:5
    const int tBlocks = (N_IN_SZ + TCOLS - 1) / TCOLS;   // 4,056 transpose tiles
    const int nsc     = (tBlocks + 3) / 4;               // 1,014 scatter blocks
    const int nGrid   = 5 * nsc;                         // 5,070 (transpose slots = 4,056)
    prep_kernel<<<nGrid, 256, 0, stream>>>(x, rows, cols, S, cursor, epad,
                                           of_count, of_list, xt, nnz);

    const int gBlocks = (N_ROWS + 63) / 64;              // 4,062
    gather_kernel<<<gBlocks, 256, 0, stream>>>(xt, cursor, epad, y);

    cleanup_kernel<<<16, 256, 0, stream>>>(of_count, of_list, x, y);
}

// Round 15
// 203.539 us; speedup vs baseline: 1.0485x; 1.0485x over previous
//
#include <hip/hip_runtime.h>
#include <hip/hip_bf16.h>

// Problem constants (from the reference)
#define N_IN_SZ   (721 * 1440)   // 1,038,240
#define N_ROWS    (361 * 720)    //   259,920 output cells
#define BC        64             // B*C = 4*16
#define ROW_CAP   16             // padded entries per row (lambda=4.03)
#define OF_CAP    4096

typedef float f32x4 __attribute__((ext_vector_type(4)));

// ---------------- fused prep (R7/R12 structure) + NT xt stores ----------------
// scatter: every 5th block, grid-stride over nnz -> per-row padded buckets.
// transpose: LDS tile, float4 loads / 8B NONTEMPORAL stores (write-around L2),
// x [64][N_IN] f32 -> xt [N_IN][64] bf16.

__global__ void prep_kernel(const float* __restrict__ x,
                            const int* __restrict__ rows, const int* __restrict__ cols,
                            const float* __restrict__ S,
                            int* __restrict__ cursor, int2* __restrict__ epad,
                            int* __restrict__ of_count, int4* __restrict__ of_list,
                            __hip_bfloat16* __restrict__ xt,
                            int nnz) {
    __shared__ float tile[64][65];   // [bc][colOff]
    const int bid = blockIdx.x;

    if ((bid % 5) == 4) {
        // ---- scatter part (interleaved through the dispatch) ----
        const int nsc = gridDim.x / 5;
        const int stride = nsc * 256;
        for (int k = (bid / 5) * 256 + threadIdx.x; k < nnz; k += stride) {
            const int r = rows[k];
            const int slot = atomicAdd(&cursor[r], 1);
            if (slot < ROW_CAP) {
                epad[(size_t)r * ROW_CAP + slot] = make_int2(cols[k], __float_as_int(S[k]));
            } else {
                int o = atomicAdd(of_count, 1);
                if (o < OF_CAP) of_list[o] = make_int4(r, cols[k], __float_as_int(S[k]), 0);
            }
        }
        return;
    }

    // ---- transpose part ----
    const int t_idx = bid - (bid + 1) / 5;
    const int c0 = t_idx * 64;
    if (c0 >= N_IN_SZ) return;
    const int lane = threadIdx.x & 63;
    const int wave = threadIdx.x >> 6;   // 0..3

    if (c0 + 64 <= N_IN_SZ) {
        // fast path: float4 loads, 4 bc-rows per wave per iter
        #pragma unroll
        for (int i = 0; i < 4; ++i) {
            const int bc = wave * 16 + i * 4 + (lane >> 4);
            const int cc = 4 * (lane & 15);
            const float4 v = *(const float4*)&x[(size_t)bc * N_IN_SZ + c0 + cc];
            tile[bc][cc + 0] = v.x;
            tile[bc][cc + 1] = v.y;
            tile[bc][cc + 2] = v.z;
            tile[bc][cc + 3] = v.w;
        }
    } else {
        // tail tile (one block): scalar guarded
        for (int e = threadIdx.x; e < 64 * 64; e += 256) {
            const int bc = e >> 6, cc = e & 63;
            const int c = c0 + cc;
            tile[bc][cc] = (c < N_IN_SZ) ? x[(size_t)bc * N_IN_SZ + c] : 0.f;
        }
    }
    __syncthreads();

    // store: 8B NT store per lane (4 bc), 4 c-rows per wave per iter -> 512B/wave-instr
    #pragma unroll
    for (int i = 0; i < 4; ++i) {
        const int cl = wave * 16 + i * 4 + (lane >> 4);
        const int c = c0 + cl;
        if (c < N_IN_SZ) {
            const int bc4 = 4 * (lane & 15);
            __hip_bfloat16 h0 = __float2bfloat16(tile[bc4 + 0][cl]);
            __hip_bfloat16 h1 = __float2bfloat16(tile[bc4 + 1][cl]);
            __hip_bfloat16 h2 = __float2bfloat16(tile[bc4 + 2][cl]);
            __hip_bfloat16 h3 = __float2bfloat16(tile[bc4 + 3][cl]);
            unsigned long long p =
                (unsigned long long)(*(unsigned short*)&h0)        |
                ((unsigned long long)(*(unsigned short*)&h1) << 16) |
                ((unsigned long long)(*(unsigned short*)&h2) << 32) |
                ((unsigned long long)(*(unsigned short*)&h3) << 48);
            __builtin_nontemporal_store(p, (unsigned long long*)&xt[(size_t)c * 64 + bc4]);
        }
    }
}

// ---------------- gather (R12, proven): 4 streams x batch-4 = 16 loads in flight ----
// y writeout via NT stores (never re-read).

__global__ void gather_kernel(const __hip_bfloat16* __restrict__ xt,
                              const int* __restrict__ cursor,
                              const int2* __restrict__ epad,
                              float* __restrict__ y) {
    __shared__ float tile[64][65];
    __shared__ int cnt[64];
    const int b = blockIdx.x;
    const int base = b * 64;
    const int lane = threadIdx.x & 63;
    const int wave = threadIdx.x >> 6;

    if (threadIdx.x < 64) {
        const int r = base + threadIdx.x;
        int cc = (r < N_ROWS) ? cursor[r] : 0;
        cnt[threadIdx.x] = (cc > ROW_CAP) ? ROW_CAP : cc;
    }
    __syncthreads();

    for (int rr = 0; rr < 4; ++rr) {
        const int r0 = wave * 16 + rr;
        const int r1 = r0 + 4;
        const int r2 = r0 + 8;
        const int r3 = r0 + 12;
        const int c0 = cnt[r0], c1 = cnt[r1], c2 = cnt[r2], c3 = cnt[r3];
        const int2* __restrict__ e0 = epad + (size_t)(base + r0) * ROW_CAP;
        const int2* __restrict__ e1 = epad + (size_t)(base + r1) * ROW_CAP;
        const int2* __restrict__ e2 = epad + (size_t)(base + r2) * ROW_CAP;
        const int2* __restrict__ e3 = epad + (size_t)(base + r3) * ROW_CAP;
        float a0 = 0.f, a1 = 0.f, a2 = 0.f, a3 = 0.f;
        int t0 = 0, t1 = 0, t2 = 0, t3 = 0;
        while (t0 < c0 || t1 < c1 || t2 < c2 || t3 < c3) {
            const bool g0 = (t0 < c0), g1 = (t1 < c1), g2 = (t2 < c2), g3 = (t3 < c3);
            const int4 z4 = make_int4(0, 0, 0, 0);
            int4 p00 = g0 ? *(const int4*)(e0 + t0)     : z4;
            int4 p01 = g0 ? *(const int4*)(e0 + t0 + 2) : z4;
            int4 p10 = g1 ? *(const int4*)(e1 + t1)     : z4;
            int4 p11 = g1 ? *(const int4*)(e1 + t1 + 2) : z4;
            int4 p20 = g2 ? *(const int4*)(e2 + t2)     : z4;
            int4 p21 = g2 ? *(const int4*)(e2 + t2 + 2) : z4;
            int4 p30 = g3 ? *(const int4*)(e3 + t3)     : z4;
            int4 p31 = g3 ? *(const int4*)(e3 + t3 + 2) : z4;
            float x00 = __bfloat162float(xt[(size_t)((t0 + 0 < c0) ? p00.x : 0) * 64 + lane]);
            float x01 = __bfloat162float(xt[(size_t)((t0 + 1 < c0) ? p00.z : 0) * 64 + lane]);
            float x02 = __bfloat162float(xt[(size_t)((t0 + 2 < c0) ? p01.x : 0) * 64 + lane]);
            float x03 = __bfloat162float(xt[(size_t)((t0 + 3 < c0) ? p01.z : 0) * 64 + lane]);
            float x10 = __bfloat162float(xt[(size_t)((t1 + 0 < c1) ? p10.x : 0) * 64 + lane]);
            float x11 = __bfloat162float(xt[(size_t)((t1 + 1 < c1) ? p10.z : 0) * 64 + lane]);
            float x12 = __bfloat162float(xt[(size_t)((t1 + 2 < c1) ? p11.x : 0) * 64 + lane]);
            float x13 = __bfloat162float(xt[(size_t)((t1 + 3 < c1) ? p11.z : 0) * 64 + lane]);
            float x20 = __bfloat162float(xt[(size_t)((t2 + 0 < c2) ? p20.x : 0) * 64 + lane]);
            float x21 = __bfloat162float(xt[(size_t)((t2 + 1 < c2) ? p20.z : 0) * 64 + lane]);
            float x22 = __bfloat162float(xt[(size_t)((t2 + 2 < c2) ? p21.x : 0) * 64 + lane]);
            float x23 = __bfloat162float(xt[(size_t)((t2 + 3 < c2) ? p21.z : 0) * 64 + lane]);
            float x30 = __bfloat162float(xt[(size_t)((t3 + 0 < c3) ? p30.x : 0) * 64 + lane]);
            float x31 = __bfloat162float(xt[(size_t)((t3 + 1 < c3) ? p30.z : 0) * 64 + lane]);
            float x32 = __bfloat162float(xt[(size_t)((t3 + 2 < c3) ? p31.x : 0) * 64 + lane]);
            float x33 = __bfloat162float(xt[(size_t)((t3 + 3 < c3) ? p31.z : 0) * 64 + lane]);
            a0 += ((t0 + 0 < c0) ? __int_as_float(p00.y) : 0.f) * x00;
            a0 += ((t0 + 1 < c0) ? __int_as_float(p00.w) : 0.f) * x01;
            a0 += ((t0 + 2 < c0) ? __int_as_float(p01.y) : 0.f) * x02;
            a0 += ((t0 + 3 < c0) ? __int_as_float(p01.w) : 0.f) * x03;
            a1 += ((t1 + 0 < c1) ? __int_as_float(p10.y) : 0.f) * x10;
            a1 += ((t1 + 1 < c1) ? __int_as_float(p10.w) : 0.f) * x11;
            a1 += ((t1 + 2 < c1) ? __int_as_float(p11.y) : 0.f) * x12;
            a1 += ((t1 + 3 < c1) ? __int_as_float(p11.w) : 0.f) * x13;
            a2 += ((t2 + 0 < c2) ? __int_as_float(p20.y) : 0.f) * x20;
            a2 += ((t2 + 1 < c2) ? __int_as_float(p20.w) : 0.f) * x21;
            a2 += ((t2 + 2 < c2) ? __int_as_float(p21.y) : 0.f) * x22;
            a2 += ((t2 + 3 < c2) ? __int_as_float(p21.w) : 0.f) * x23;
            a3 += ((t3 + 0 < c3) ? __int_as_float(p30.y) : 0.f) * x30;
            a3 += ((t3 + 1 < c3) ? __int_as_float(p30.w) : 0.f) * x31;
            a3 += ((t3 + 2 < c3) ? __int_as_float(p31.y) : 0.f) * x32;
            a3 += ((t3 + 3 < c3) ? __int_as_float(p31.w) : 0.f) * x33;
            if (g0) t0 += 4;
            if (g1) t1 += 4;
            if (g2) t2 += 4;
            if (g3) t3 += 4;
        }
        tile[lane][r0] = a0;
        tile[lane][r1] = a1;
        tile[lane][r2] = a2;
        tile[lane][r3] = a3;
    }
    __syncthreads();

    // writeout: 1024 float4 tasks = 64 bc x 16 quads; 4 per thread; NT stores
    #pragma unroll
    for (int j = 0; j < 4; ++j) {
        const int task = j * 256 + threadIdx.x;
        const int bc = task >> 4;
        const int r0 = (task & 15) * 4;
        const int i0 = base + r0;
        f32x4 v = {tile[bc][r0], tile[bc][r0 + 1], tile[bc][r0 + 2], tile[bc][r0 + 3]};
        float* yp = y + (size_t)bc * N_ROWS;
        if (i0 + 3 < N_ROWS) {
            __builtin_nontemporal_store(v, (f32x4*)&yp[i0]);
        } else {
            if (i0 + 0 < N_ROWS) yp[i0 + 0] = v.x;
            if (i0 + 1 < N_ROWS) yp[i0 + 1] = v.y;
            if (i0 + 2 < N_ROWS) yp[i0 + 2] = v.z;
            if (i0 + 3 < N_ROWS) yp[i0 + 3] = v.w;
        }
    }
}

// ---------------- overflow cleanup (expected ~0 entries) ----------------

__global__ void cleanup_kernel(const int* __restrict__ of_count,
                               const int4* __restrict__ of_list,
                               const float* __restrict__ x, float* __restrict__ y) {
    int n = *of_count;
    if (n > OF_CAP) n = OF_CAP;
    const int total = n * 64;
    for (int t = blockIdx.x * blockDim.x + threadIdx.x; t < total;
         t += gridDim.x * blockDim.x) {
        const int e = t >> 6, bc = t & 63;
        const int4 E = of_list[e];
        atomicAdd(&y[(size_t)bc * N_ROWS + E.x],
                  __int_as_float(E.z) * x[(size_t)bc * N_IN_SZ + E.y]);
    }
}

// ---------------- last-resort atomic COO ----------------

__global__ void regrid_coo_kernel(const float* __restrict__ x, const float* __restrict__ S,
                                  const int* __restrict__ rows, const int* __restrict__ cols,
                                  float* __restrict__ y, int nnz) {
    const int bc = blockIdx.y;
    const float* __restrict__ xp = x + (size_t)bc * N_IN_SZ;
    float* __restrict__ yp = y + (size_t)bc * N_ROWS;
    int k = blockIdx.x * blockDim.x + threadIdx.x;
    const int stride = gridDim.x * blockDim.x;
    for (; k < nnz; k += stride) {
        atomicAdd(&yp[rows[k]], S[k] * xp[cols[k]]);
    }
}

extern "C" void kernel_launch(void* const* d_in, const int* in_sizes, int n_in,
                              void* d_out, int out_size, void* d_ws, size_t ws_size,
                              hipStream_t stream) {
    const float* x    = (const float*)d_in[0];
    const float* S    = (const float*)d_in[1];
    const int*   rows = (const int*)d_in[2];
    const int*   cols = (const int*)d_in[3];
    float*       y    = (float*)d_out;
    const int nnz = in_sizes[1];

    // Workspace layout (256B-aligned chunks)
    const size_t SZ_CURSOR = ((size_t)N_ROWS * 4 + 255) & ~255ULL;             // 1.04 MB
    const size_t SZ_OFCNT  = 256;
    const size_t SZ_OFLIST = ((size_t)OF_CAP * 16 + 255) & ~255ULL;            // 64 KB
    const size_t SZ_EPAD   = ((size_t)N_ROWS * ROW_CAP * 8 + 255) & ~255ULL;   // 33.3 MB
    const size_t SZ_XT     = ((size_t)N_IN_SZ * BC * 2 + 255) & ~255ULL;       // 133 MB
    const size_t NEED = SZ_CURSOR + SZ_OFCNT + SZ_OFLIST + SZ_EPAD + SZ_XT;

    if (ws_size < NEED) {
        hipMemsetAsync(d_out, 0, (size_t)out_size * sizeof(float), stream);
        dim3 grid(1024, BC, 1);
        regrid_coo_kernel<<<grid, 256, 0, stream>>>(x, S, rows, cols, y, nnz);
        return;
    }

    char* w = (char*)d_ws;
    int*  cursor   = (int*)(w);
    int*  of_count = (int*)(w + SZ_CURSOR);
    int4* of_list  = (int4*)(w + SZ_CURSOR + SZ_OFCNT);
    int2* epad     = (int2*)(w + SZ_CURSOR + SZ_OFCNT + SZ_OFLIST);
    __hip_bfloat16* xt = (__hip_bfloat16*)(w + SZ_CURSOR + SZ_OFCNT + SZ_OFLIST + SZ_EPAD);

    // zero cursors + overflow count in one memset (contiguous)
    hipMemsetAsync(cursor, 0, SZ_CURSOR + SZ_OFCNT, stream);

    // fused prep: ~1/5 scatter blocks interleaved with transpose blocks (R7 structure)
    const int tBlocks = (N_IN_SZ + 63) / 64;          // 16,223 transpose tiles
    const int nBlocks = ((tBlocks + 4096) / 4) * 5;   // ~1/5 scatter, rest transpose
    prep_kernel<<<nBlocks, 256, 0, stream>>>(x, rows, cols, S, cursor, epad,
                                             of_count, of_list, xt, nnz);

    const int gBlocks = (N_ROWS + 63) / 64;           // 4,062
    gather_kernel<<<gBlocks, 256, 0, stream>>>(xt, cursor, epad, y);

    cleanup_kernel<<<16, 256, 0, stream>>>(of_count, of_list, x, y);
}